// Round 13
// baseline (470.141 us; speedup 1.0000x reference)
//
#include <hip/hip_runtime.h>
#include <cstdint>

typedef unsigned short u16;
typedef unsigned int u32;
typedef __attribute__((ext_vector_type(8))) short short8;   // 8 bf16 (MFMA A/B frag)
typedef __attribute__((ext_vector_type(4))) float floatx4;  // MFMA C/D frag
typedef __attribute__((ext_vector_type(2))) float floatx2;  // packed f32 pair (v_pk_*_f32)

__device__ __forceinline__ float b2f(u16 u) {
    union { unsigned int i; float f; } c; c.i = ((unsigned int)u) << 16; return c.f;
}
__device__ __forceinline__ u16 f2b(float f) {
    union { float f; unsigned int i; } c; c.f = f;
    unsigned int u = c.i;
    u = u + 0x7FFFu + ((u >> 16) & 1u);   // RNE
    return (u16)(u >> 16);
}
__device__ __forceinline__ float u2f(u32 u) { union { u32 u; float f; } c; c.u = u; return c.f; }

// global -> LDS direct staging, 16B per lane, zero VGPR cost.
__device__ __forceinline__ void kstage(const u16* gsrc, u16* ldst) {
    __builtin_amdgcn_global_load_lds(
        (const __attribute__((address_space(1))) u32*)gsrc,
        (__attribute__((address_space(3))) u32*)ldst, 16, 0, 0);
}

// ---------------------------------------------------------------------------
// Fused Q/K/V projection GEMM. Y[m,n] = sum_k x[m,k]*W[n,k] + bias[n].
// grid (32, 24): which = blockIdx.y>>3 (0=q fp32, 1=k bf16, 2=v -> vt hi/lo bf16 transposed).
// ---------------------------------------------------------------------------
__global__ __launch_bounds__(256) void gemm_qkv(
    const float* __restrict__ x,
    const float* __restrict__ Wq, const float* __restrict__ Wk, const float* __restrict__ Wv,
    const float* __restrict__ bq, const float* __restrict__ bk, const float* __restrict__ bv,
    float* __restrict__ qout, u16* __restrict__ kout,
    u16* __restrict__ vthi, u16* __restrict__ vtlo)
{
    __shared__ u16 xs[64 * 72];
    __shared__ u16 wsl[64 * 72];
    int tid = threadIdx.x;
    int lane = tid & 63;
    int wv = tid >> 6;
    int lo = lane & 15, hi = lane >> 4;
    int which = blockIdx.y >> 3;
    int m0 = blockIdx.x * 64, n0 = (blockIdx.y & 7) * 64;
    const float* W    = which == 0 ? Wq : (which == 1 ? Wk : Wv);
    const float* bias = which == 0 ? bq : (which == 1 ? bk : bv);

    floatx4 acc[4];
#pragma unroll
    for (int mt = 0; mt < 4; ++mt) acc[mt] = (floatx4){0.f, 0.f, 0.f, 0.f};

    for (int k0 = 0; k0 < 512; k0 += 64) {
        __syncthreads();
#pragma unroll
        for (int i = 0; i < 2; ++i) {
            int v = tid + i * 256;
            int row = v >> 3, c8 = (v & 7) * 8;
            const float* ap = x + (m0 + row) * 512 + k0 + c8;
            const float* wp = W + (n0 + row) * 512 + k0 + c8;
            float4 a0 = *(const float4*)(ap);
            float4 a1 = *(const float4*)(ap + 4);
            float4 w0 = *(const float4*)(wp);
            float4 w1v = *(const float4*)(wp + 4);
            union { u16 u[8]; uint4 q; } ca, cw;
            ca.u[0] = f2b(a0.x); ca.u[1] = f2b(a0.y); ca.u[2] = f2b(a0.z); ca.u[3] = f2b(a0.w);
            ca.u[4] = f2b(a1.x); ca.u[5] = f2b(a1.y); ca.u[6] = f2b(a1.z); ca.u[7] = f2b(a1.w);
            cw.u[0] = f2b(w0.x); cw.u[1] = f2b(w0.y); cw.u[2] = f2b(w0.z); cw.u[3] = f2b(w0.w);
            cw.u[4] = f2b(w1v.x); cw.u[5] = f2b(w1v.y); cw.u[6] = f2b(w1v.z); cw.u[7] = f2b(w1v.w);
            *(uint4*)(xs + row * 72 + c8)  = ca.q;
            *(uint4*)(wsl + row * 72 + c8) = cw.q;
        }
        __syncthreads();
#pragma unroll
        for (int ks = 0; ks < 2; ++ks) {
            short8 bfr = *(const short8*)(wsl + (wv * 16 + lo) * 72 + ks * 32 + hi * 8);
#pragma unroll
            for (int mt = 0; mt < 4; ++mt) {
                short8 afr = *(const short8*)(xs + (mt * 16 + lo) * 72 + ks * 32 + hi * 8);
                acc[mt] = __builtin_amdgcn_mfma_f32_16x16x32_bf16(afr, bfr, acc[mt], 0, 0, 0);
            }
        }
    }

    int n = n0 + wv * 16 + lo;
    float bv2 = bias[n];
    if (which == 2) {
        // transpose V tile through LDS; emit vt_hi/vt_lo bf16 [bh][d][c]
        __syncthreads();                           // xs/wsl reuse: all waves done with MFMAs
        int nl = wv * 16 + lo;                     // local d
#pragma unroll
        for (int mt = 0; mt < 4; ++mt)
#pragma unroll
            for (int r = 0; r < 4; ++r) {
                int ml = mt * 16 + hi * 4 + r;     // local c
                float y = acc[mt][r] + bv2;
                u16 vh = f2b(y);
                u16 vl = f2b(y - b2f(vh));
                xs[nl * 72 + ml]  = vh;
                wsl[nl * 72 + ml] = vl;
            }
        __syncthreads();
        int row = tid >> 2, seg = (tid & 3) * 16;  // row = local d, seg = local c chunk
        int b = m0 >> 10, c0 = m0 & 1023, h2 = n0 >> 6;
        size_t dst = ((size_t)((b * 8 + h2) * 64 + row)) * 1024 + c0 + seg;
        *(uint4*)(vthi + dst)     = *(uint4*)(xs  + row * 72 + seg);
        *(uint4*)(vthi + dst + 8) = *(uint4*)(xs  + row * 72 + seg + 8);
        *(uint4*)(vtlo + dst)     = *(uint4*)(wsl + row * 72 + seg);
        *(uint4*)(vtlo + dst + 8) = *(uint4*)(wsl + row * 72 + seg + 8);
    } else {
        int h = n >> 6, dd = n & 63;
#pragma unroll
        for (int mt = 0; mt < 4; ++mt)
#pragma unroll
            for (int r = 0; r < 4; ++r) {
                int m = m0 + mt * 16 + hi * 4 + r;  // C/D: row=(lane>>4)*4+reg, col=lane&15
                float y = acc[mt][r] + bv2;
                int b = m >> 10, c = m & 1023;
                int idx = (((b * 8 + h) * 1024) + c) * 64 + dd;
                if (which == 0) qout[idx] = y;
                else            kout[idx] = f2b(y);
            }
    }
}

// ---------------------------------------------------------------------------
// Output GEMM: Y[m,n] = sum_k A[m,k]*Wo[n,k] + bo[n], fp32 out, [m*512+n].
// ---------------------------------------------------------------------------
__global__ __launch_bounds__(256) void gemm_out(
    const float* __restrict__ A, const float* __restrict__ W, const float* __restrict__ bias,
    float* __restrict__ outf)
{
    __shared__ u16 xs[64 * 72];
    __shared__ u16 wsl[64 * 72];
    int tid = threadIdx.x;
    int lane = tid & 63;
    int wv = tid >> 6;
    int lo = lane & 15, hi = lane >> 4;
    int m0 = blockIdx.x * 64, n0 = blockIdx.y * 64;

    floatx4 acc[4];
#pragma unroll
    for (int mt = 0; mt < 4; ++mt) acc[mt] = (floatx4){0.f, 0.f, 0.f, 0.f};

    for (int k0 = 0; k0 < 512; k0 += 64) {
        __syncthreads();
#pragma unroll
        for (int i = 0; i < 2; ++i) {
            int v = tid + i * 256;
            int row = v >> 3, c8 = (v & 7) * 8;
            const float* ap = A + (m0 + row) * 512 + k0 + c8;
            const float* wp = W + (n0 + row) * 512 + k0 + c8;
            float4 a0 = *(const float4*)(ap);
            float4 a1 = *(const float4*)(ap + 4);
            float4 w0 = *(const float4*)(wp);
            float4 w1v = *(const float4*)(wp + 4);
            union { u16 u[8]; uint4 q; } ca, cw;
            ca.u[0] = f2b(a0.x); ca.u[1] = f2b(a0.y); ca.u[2] = f2b(a0.z); ca.u[3] = f2b(a0.w);
            ca.u[4] = f2b(a1.x); ca.u[5] = f2b(a1.y); ca.u[6] = f2b(a1.z); ca.u[7] = f2b(a1.w);
            cw.u[0] = f2b(w0.x); cw.u[1] = f2b(w0.y); cw.u[2] = f2b(w0.z); cw.u[3] = f2b(w0.w);
            cw.u[4] = f2b(w1v.x); cw.u[5] = f2b(w1v.y); cw.u[6] = f2b(w1v.z); cw.u[7] = f2b(w1v.w);
            *(uint4*)(xs + row * 72 + c8)  = ca.q;
            *(uint4*)(wsl + row * 72 + c8) = cw.q;
        }
        __syncthreads();
#pragma unroll
        for (int ks = 0; ks < 2; ++ks) {
            short8 bfr = *(const short8*)(wsl + (wv * 16 + lo) * 72 + ks * 32 + hi * 8);
#pragma unroll
            for (int mt = 0; mt < 4; ++mt) {
                short8 afr = *(const short8*)(xs + (mt * 16 + lo) * 72 + ks * 32 + hi * 8);
                acc[mt] = __builtin_amdgcn_mfma_f32_16x16x32_bf16(afr, bfr, acc[mt], 0, 0, 0);
            }
        }
    }

    int n = n0 + wv * 16 + lo;
    float bv = bias[n];
#pragma unroll
    for (int mt = 0; mt < 4; ++mt)
#pragma unroll
        for (int r = 0; r < 4; ++r) {
            int m = m0 + mt * 16 + hi * 4 + r;
            outf[m * 512 + n] = acc[mt][r] + bv;
        }
}

// ---------------------------------------------------------------------------
// Fused second-order attention, v25 = v24 (LDS-staged K + both-sides swizzle,
// 403 us) + DEFERRED SOFTMAX TAIL: the per-chunk shfl/exp2/f2b/publish tail
// is moved one chunk later, executed right after the next chunk's ds_read
// issue -- its ~130 cyc of independent work covers the chunk-top
// ds_read_b128 -> MFMA latency (the remaining 26%-idle signature). Only
// s0p/s1p (+2 regs) carried across the barrier.
// Publish timing: plane 3 of group g's buffer lands at top of chunk 4g+4
// (after barrier 4g+3); PV(group g) moves to top of chunk 1 of group g+1
// (one barrier later -> all 4 planes visible). Next write to that buffer is
// 4 barriers after the PV. Epilogue: TAIL(31) + barrier + PV(group 7).
// Math order-identical to v24 (passed, absmax 7.3e-4).
// ---------------------------------------------------------------------------
#define CHUNK_LOAD(BUFI)                                                       \
    {                                                                          \
        bf[0][0] = *(const short8*)(kr0 + (BUFI) * 2048);                      \
        bf[0][1] = *(const short8*)(kr1 + (BUFI) * 2048);                      \
        bf[1][0] = *(const short8*)(kr0 + (BUFI) * 2048 + 1024);               \
        bf[1][1] = *(const short8*)(kr1 + (BUFI) * 2048 + 1024);               \
        kstage(kg, kstg + (((BUFI) ^ 1) * 2048));                              \
        kg += 2048;                                                            \
    }

// deferred tail of the PREVIOUS chunk: wave-local shfl reduce + softmax
// numerator + publish into (BUF) plane (PLANE). Covers this chunk's ds_read.
#define TAIL(BUF, PLANE)                                                       \
    {                                                                          \
        float t0 = s0p, t1 = s1p;                                              \
        t0 += __shfl_xor(t0, 16); t0 += __shfl_xor(t0, 32);                    \
        t1 += __shfl_xor(t1, 16); t1 += __shfl_xor(t1, 32);                    \
        float p0 = __builtin_amdgcn_exp2f(t0 - 16.0f);                         \
        float p1 = __builtin_amdgcn_exp2f(t1 - 16.0f);                         \
        u16 ph0 = f2b(p0);                                                     \
        u16 ph1 = f2b(p1);                                                     \
        l_run += b2f(ph0) + b2f(ph1);                                          \
        u16* pw = (BUF) + (PLANE) * 528;                                       \
        if (lane < 16) {                                                       \
            pw[((lo >> 3) * 16 + wv) * 8 + (lo & 7)] = ph0;                    \
            pw[((2 + (lo >> 3)) * 16 + wv) * 8 + (lo & 7)] = ph1;              \
        }                                                                      \
    }

#define CHUNK_SCORE                                                            \
    {                                                                          \
        floatx2 s0v = (floatx2){0.f, 0.f};                                     \
        floatx2 s1v = (floatx2){0.f, 0.f};                                     \
        floatx4 aP[2], aN[2];                                                  \
        aP[0] = __builtin_amdgcn_mfma_f32_16x16x32_bf16(af[0][0], bf[0][0], qpinit[0], 0, 0, 0); \
        aP[0] = __builtin_amdgcn_mfma_f32_16x16x32_bf16(af[0][1], bf[0][1], aP[0], 0, 0, 0); \
        aP[1] = __builtin_amdgcn_mfma_f32_16x16x32_bf16(af[0][0], bf[1][0], qpinit[0], 0, 0, 0); \
        aP[1] = __builtin_amdgcn_mfma_f32_16x16x32_bf16(af[0][1], bf[1][1], aP[1], 0, 0, 0); \
        _Pragma("unroll")                                                      \
        for (int mt = 0; mt < 4; ++mt) {                                       \
            if (mt < 3) {                                                      \
                aN[0] = __builtin_amdgcn_mfma_f32_16x16x32_bf16(af[mt + 1][0], bf[0][0], qpinit[mt + 1], 0, 0, 0); \
                aN[0] = __builtin_amdgcn_mfma_f32_16x16x32_bf16(af[mt + 1][1], bf[0][1], aN[0], 0, 0, 0); \
                aN[1] = __builtin_amdgcn_mfma_f32_16x16x32_bf16(af[mt + 1][0], bf[1][0], qpinit[mt + 1], 0, 0, 0); \
                aN[1] = __builtin_amdgcn_mfma_f32_16x16x32_bf16(af[mt + 1][1], bf[1][1], aN[1], 0, 0, 0); \
            }                                                                  \
            _Pragma("unroll")                                                  \
            for (int h2 = 0; h2 < 2; ++h2) {                                   \
                u32 wp = wcp[mt][h2];                                          \
                floatx2 wv2 = (floatx2){u2f(wp << 16), u2f(wp & 0xFFFF0000u)}; \
                _Pragma("unroll")                                              \
                for (int t = 0; t < 2; ++t) {                                  \
                    floatx2 x = (floatx2){aP[t][h2 * 2 + 0], aP[t][h2 * 2 + 1]}; \
                    floatx2 ex = (floatx2){__builtin_amdgcn_exp2f(x.x),        \
                                           __builtin_amdgcn_exp2f(x.y)};       \
                    floatx2 a = ex + 1.0f;                                     \
                    float rc = __builtin_amdgcn_rcpf(a.x * a.y);               \
                    floatx2 sw = (floatx2){a.y, a.x};                          \
                    floatx2 contrib = (x * wv2) * (sw * rc);                   \
                    if (t == 0) s0v += contrib; else s1v += contrib;           \
                }                                                              \
            }                                                                  \
            aP[0] = aN[0];                                                     \
            aP[1] = aN[1];                                                     \
        }                                                                      \
        s0p = s0v.x + s0v.y;                                                   \
        s1p = s1v.x + s1v.y;                                                   \
    }

#define PV_GROUP(PGW)                                                          \
    {                                                                          \
        const u16* vlp = vhp + (1u << 20);         /* vtlo = vthi + 2MB */     \
        _Pragma("unroll")                                                      \
        for (int c2 = 0; c2 < 4; ++c2) {                                       \
            uint4 vh = *(const uint4*)(vhp + c2 * 32);                         \
            uint4 vl = *(const uint4*)(vlp + c2 * 32);                         \
            short8 pf = *(const short8*)((PGW) + c2 * 528 + lane * 8);         \
            pvacc = __builtin_amdgcn_mfma_f32_16x16x32_bf16(pf, *(short8*)&vh, pvacc, 0, 0, 0); \
            pvacc = __builtin_amdgcn_mfma_f32_16x16x32_bf16(pf, *(short8*)&vl, pvacc, 0, 0, 0); \
        }                                                                      \
        vhp += 128;                                                            \
    }

__global__ __launch_bounds__(256, 4) void attn25(
    const float* __restrict__ qf, const u16* __restrict__ kb,
    const u16* __restrict__ vthi, const u16* __restrict__ vtlo,
    const float* __restrict__ w1, const float* __restrict__ b1, const float* __restrict__ w2,
    float* __restrict__ ao)
{
    __shared__ float q_l[4 * 64];
    __shared__ __align__(16) u16 plds[2 * 4 * 528];   // [dbuf][chunk plane 528][A-frag order]
    __shared__ __align__(16) u16 kbuf[2 * 2048];      // 2 x 4KB K-chunk ring (col-swizzled)
    __shared__ float l_sh[4];
    int tid = threadIdx.x;
    int lane = tid & 63;
    int wv = tid >> 6;
    int lo = lane & 15, hi = lane >> 4;
    int bh = blockIdx.x >> 8;                      // 0..15 = b*8+h
    int qbase = (blockIdx.x & 255) << 2;           // block's first query
    int qi = qbase | wv;                           // this wave's query

    const float NA = -2.45546696f;                 // -1.702 * log2(e)

    // zero p-LDS once: A-frag rows q=4..15 must stay 0 so PV C rows 4..15 are clean
    for (int i = tid; i < 2112; i += 256) ((u32*)plds)[i] = 0;

    q_l[wv * 64 + lane] = qf[(bh * 1024 + qi) * 64 + lane];

    // qp[e]+b1[e] at lane=e
    float qpacc = b1[lane];
#pragma unroll
    for (int d8 = 0; d8 < 64; d8 += 8) {
        float4 wa = *(const float4*)(w1 + lane * 192 + d8);
        float4 wb = *(const float4*)(w1 + lane * 192 + d8 + 4);
        const float* q8 = q_l + wv * 64 + d8;      // wave-uniform broadcast reads
        qpacc = __builtin_fmaf(q8[0], wa.x, qpacc);
        qpacc = __builtin_fmaf(q8[1], wa.y, qpacc);
        qpacc = __builtin_fmaf(q8[2], wa.z, qpacc);
        qpacc = __builtin_fmaf(q8[3], wa.w, qpacc);
        qpacc = __builtin_fmaf(q8[4], wb.x, qpacc);
        qpacc = __builtin_fmaf(q8[5], wb.y, qpacc);
        qpacc = __builtin_fmaf(q8[6], wb.z, qpacc);
        qpacc = __builtin_fmaf(q8[7], wb.w, qpacc);
    }
    qpacc *= NA;                                   // qp' = c * (qp + b1)

    // w2c packed: wc' = w2[e] * (1/8)*log2e / c = w2[e] * -0.07344288
    u32 wcp[4][2];
    float w2row = w2[lane] * -0.07344288f;
#pragma unroll
    for (int mt = 0; mt < 4; ++mt)
#pragma unroll
        for (int h2 = 0; h2 < 2; ++h2) {
            int e0 = mt * 16 + hi * 4 + h2 * 2;
            u32 lo16 = (u32)f2b(__shfl(w2row, e0));
            u32 hi16 = (u32)f2b(__shfl(w2row, e0 + 1));
            wcp[mt][h2] = (hi16 << 16) | lo16;
        }

    // q pieces for frag build: qv2[ks][j] = q[ks*32 + hi*8 + j]
    float qv2[2][8];
#pragma unroll
    for (int ks = 0; ks < 2; ++ks)
#pragma unroll
        for (int j = 0; j < 8; ++j)
            qv2[ks][j] = q_l[wv * 64 + ks * 32 + hi * 8 + j];

    // A-frags: c * qw'[e = mt*16+lo][dd = ks*32 + hi*8 + j], bf16
    short8 af[4][2];
#pragma unroll
    for (int mt = 0; mt < 4; ++mt) {
        const float* wr = w1 + (mt * 16 + lo) * 192;
#pragma unroll
        for (int ks = 0; ks < 2; ++ks) {
            int dd0 = ks * 32 + hi * 8;
            float4 a0 = *(const float4*)(wr + 128 + dd0);
            float4 a1 = *(const float4*)(wr + 128 + dd0 + 4);
            float4 k0 = *(const float4*)(wr + 64 + dd0);
            float4 k1 = *(const float4*)(wr + 64 + dd0 + 4);
            union { u16 u[8]; short8 s; } cv;
            cv.u[0] = f2b(NA * __builtin_fmaf(qv2[ks][0], a0.x, k0.x));
            cv.u[1] = f2b(NA * __builtin_fmaf(qv2[ks][1], a0.y, k0.y));
            cv.u[2] = f2b(NA * __builtin_fmaf(qv2[ks][2], a0.z, k0.z));
            cv.u[3] = f2b(NA * __builtin_fmaf(qv2[ks][3], a0.w, k0.w));
            cv.u[4] = f2b(NA * __builtin_fmaf(qv2[ks][4], a1.x, k1.x));
            cv.u[5] = f2b(NA * __builtin_fmaf(qv2[ks][5], a1.y, k1.y));
            cv.u[6] = f2b(NA * __builtin_fmaf(qv2[ks][6], a1.z, k1.z));
            cv.u[7] = f2b(NA * __builtin_fmaf(qv2[ks][7], a1.w, k1.w));
            af[mt][ks] = cv.s;
        }
    }

    // rank-1 qp' C-init, loop-invariant (v18-verified)
    floatx4 qpinit[4];
    {
        const floatx4 z = (floatx4){0.f, 0.f, 0.f, 0.f};
        union { u16 u[8]; short8 s; } bb;
#pragma unroll
        for (int i = 0; i < 8; ++i) bb.u[i] = 0;
        bb.u[0] = (hi == 0) ? (u16)0x3F80 : (u16)0;   // bf16 1.0 at k=0
#pragma unroll
        for (int mt = 0; mt < 4; ++mt) {
            float qpv = __shfl(qpacc, mt * 16 + lo);
            union { u16 u[8]; short8 s; } aa;
#pragma unroll
            for (int i = 0; i < 8; ++i) aa.u[i] = 0;
            aa.u[0] = (hi == 0) ? f2b(qpv) : (u16)0;
            qpinit[mt] = __builtin_amdgcn_mfma_f32_16x16x32_bf16(aa.s, bb.s, z, 0, 0, 0);
        }
    }

    // K staging source with col-swizzle pre-applied on the GLOBAL address:
    // lane's LDS slot s = wv*64+lane holds (row = s>>3, col = s&7); it must
    // load global 16B unit (row, col ^ (row&7)). row&7 = lane>>3 here.
    const u16* kg = kb + bh * 65536
                  + (wv * 8 + (lane >> 3)) * 64
                  + (((lane & 7) ^ (lane >> 3)) * 8);
    u16* kstg = kbuf + wv * 512;                   // linear LDS dest (wave-uniform + lane*16B)
    kstage(kg, kstg);                              // stage chunk 0 into kbuf[0]
    kg += 2048;

    // swizzled per-lane read bases: row lo, cols ksw / ksw^4 (rows +16 share lo&7)
    int ksw = hi ^ (lo & 7);
    const u16* kr0 = kbuf + lo * 64 + ksw * 8;
    const u16* kr1 = kbuf + lo * 64 + (ksw ^ 4) * 8;

    // drains chunk-0 staging (vmcnt) + plds zero-init + q_l, block-wide
    __syncthreads();

    float l_run = 0.f;
    float s0p = 0.f, s1p = 0.f;                    // deferred-tail carry (+2 regs)
    floatx4 pvacc = (floatx4){0.f, 0.f, 0.f, 0.f};   // out[q=row 0..3][d = wv*16+col]
    // V^T B-frag base: this wave's d-tile row = wv*16+lo, k-offset hi*8
    const u16* vhp = vthi + bh * 65536 + (wv * 16 + lo) * 1024 + hi * 8;
    short8 bf[2][2];

    for (int g = 0; g < 8; ++g) {
        u16* gw = plds + (g & 1) * (4 * 528);          // this group's write buffer
        u16* ow = plds + ((g & 1) ^ 1) * (4 * 528);    // other (previous group's) buffer

        // chunk 4g+0 (kbuf parity 0); deferred tail = chunk 4(g-1)+3 -> ow plane 3
        CHUNK_LOAD(0)
        if (g > 0) { TAIL(ow, 3) }
        CHUNK_SCORE
        __syncthreads();
        // chunk 4g+1; tail = chunk 4g+0 -> gw plane 0; PV for group g-1 (ow complete)
        CHUNK_LOAD(1)
        TAIL(gw, 0)
        if (g > 0) { PV_GROUP(ow) }
        CHUNK_SCORE
        __syncthreads();
        // chunk 4g+2; tail = chunk 4g+1 -> gw plane 1
        CHUNK_LOAD(0)
        TAIL(gw, 1)
        CHUNK_SCORE
        __syncthreads();
        // chunk 4g+3; tail = chunk 4g+2 -> gw plane 2
        CHUNK_LOAD(1)
        TAIL(gw, 2)
        CHUNK_SCORE
        __syncthreads();
    }

    // epilogue: tail of chunk 31 -> plds[1] plane 3, then PV for group 7
    TAIL(plds + (4 * 528), 3)
    __syncthreads();
    PV_GROUP(plds + (4 * 528))

    float l = l_run;
    l += __shfl_xor(l, 1); l += __shfl_xor(l, 2);
    l += __shfl_xor(l, 4); l += __shfl_xor(l, 8);
    if (lane == 0) l_sh[wv] = l;
    __syncthreads();

    if (hi == 0) {                                 // C rows 0..3 live on lanes 0..15
        int b = bh >> 3, h = bh & 7;
#pragma unroll
        for (int q = 0; q < 4; ++q) {
            float outv = pvacc[q] * __builtin_amdgcn_rcpf(l_sh[q]);
            ao[((b * 1024 + qbase + q) * 512) + h * 64 + wv * 16 + lo] = outv;
        }
    }
}
#undef CHUNK_LOAD
#undef CHUNK_SCORE
#undef TAIL
#undef PV_GROUP

// ---------------------------------------------------------------------------
extern "C" void kernel_launch(void* const* d_in, const int* in_sizes, int n_in,
                              void* d_out, int out_size, void* d_ws, size_t ws_size,
                              hipStream_t stream)
{
    (void)in_sizes; (void)n_in; (void)out_size; (void)ws_size;
    const float* x  = (const float*)d_in[0];
    const float* Wq = (const float*)d_in[1];
    const float* bq = (const float*)d_in[2];
    const float* Wk = (const float*)d_in[3];
    const float* bk = (const float*)d_in[4];
    const float* Wv = (const float*)d_in[5];
    const float* bv = (const float*)d_in[6];
    const float* w1 = (const float*)d_in[7];
    const float* b1 = (const float*)d_in[8];
    const float* w2 = (const float*)d_in[9];
    // d_in[10] = b2: scalar shift of all scores -> softmax-invariant -> unused
    const float* Wo = (const float*)d_in[11];
    const float* bo = (const float*)d_in[12];

    char* ws = (char*)d_ws;
    float* q_ws = (float*)(ws);               // 4 MB fp32 (b,h,c,d)
    u16*   k_ws = (u16*)(ws + (4u << 20));    // 2 MB bf16 (b,h,c,d)
    u16*   vthi = (u16*)(ws + (6u << 20));    // 2 MB bf16 V^T hi (b,h,d,c)
    u16*   vtlo = (u16*)(ws + (8u << 20));    // 2 MB bf16 V^T lo (b,h,d,c) (MUST stay vthi+2MB)
    float* a_ws = (float*)(ws + (10u << 20)); // 4 MB fp32 (b,c,D)

    dim3 blk(256);
    hipLaunchKernelGGL(gemm_qkv, dim3(32, 24), blk, 0, stream,
                       x, Wq, Wk, Wv, bq, bk, bv, q_ws, k_ws, vthi, vtlo);
    hipLaunchKernelGGL(attn25, dim3(4096), blk, 0, stream,
                       q_ws, k_ws, vthi, vtlo, w1, b1, w2, a_ws);
    hipLaunchKernelGGL(gemm_out, dim3(32, 8), blk, 0, stream, a_ws, Wo, bo, (float*)d_out);
}

// Round 14
// 447.778 us; speedup vs baseline: 1.0499x; 1.0499x over previous
//
#include <hip/hip_runtime.h>
#include <cstdint>

typedef unsigned short u16;
typedef unsigned int u32;
typedef __attribute__((ext_vector_type(8))) short short8;   // 8 bf16 (MFMA A/B frag)
typedef __attribute__((ext_vector_type(4))) float floatx4;  // MFMA C/D frag
typedef __attribute__((ext_vector_type(2))) float floatx2;  // packed f32 pair (v_pk_*_f32)

__device__ __forceinline__ float b2f(u16 u) {
    union { unsigned int i; float f; } c; c.i = ((unsigned int)u) << 16; return c.f;
}
__device__ __forceinline__ u16 f2b(float f) {
    union { float f; unsigned int i; } c; c.f = f;
    unsigned int u = c.i;
    u = u + 0x7FFFu + ((u >> 16) & 1u);   // RNE
    return (u16)(u >> 16);
}
__device__ __forceinline__ float u2f(u32 u) { union { u32 u; float f; } c; c.u = u; return c.f; }

// global -> LDS direct staging, 16B per lane, zero VGPR cost.
__device__ __forceinline__ void kstage(const u16* gsrc, u16* ldst) {
    __builtin_amdgcn_global_load_lds(
        (const __attribute__((address_space(1))) u32*)gsrc,
        (__attribute__((address_space(3))) u32*)ldst, 16, 0, 0);
}

// ---------------------------------------------------------------------------
// Pre-convert x, Wq, Wk, Wv to bf16 (RNE, identical f2b as before -> results
// byte-identical). Outputs overlay the a_ws region (free until attn writes it;
// gemm_qkv consumes them first; launches are serial on one stream).
// Concatenated u16 layout: xb[1048576] | wqb[262144] | wkb[262144] | wvb[262144]
// = 1,835,008 u16 = 229,376 uint4 stores. grid 896 x 256 = exactly that.
// ---------------------------------------------------------------------------
__global__ __launch_bounds__(256) void convert_bf16(
    const float* __restrict__ x,  const float* __restrict__ Wq,
    const float* __restrict__ Wk, const float* __restrict__ Wv,
    u16* __restrict__ outb)
{
    int idx = blockIdx.x * 256 + threadIdx.x;      // uint4 index
    int e = idx * 8;                               // element index (concatenated)
    const float* src;
    if (e < 1048576)      src = x  + e;
    else if (e < 1310720) src = Wq + (e - 1048576);
    else if (e < 1572864) src = Wk + (e - 1310720);
    else                  src = Wv + (e - 1572864);
    float4 a0 = *(const float4*)(src);
    float4 a1 = *(const float4*)(src + 4);
    union { u16 u[8]; uint4 q; } c;
    c.u[0] = f2b(a0.x); c.u[1] = f2b(a0.y); c.u[2] = f2b(a0.z); c.u[3] = f2b(a0.w);
    c.u[4] = f2b(a1.x); c.u[5] = f2b(a1.y); c.u[6] = f2b(a1.z); c.u[7] = f2b(a1.w);
    *(uint4*)(outb + e) = c.q;
}

// ---------------------------------------------------------------------------
// Fused Q/K/V projection GEMM, bf16 inputs. Y[m,n] = sum_k x[m,k]*W[n,k]+b[n].
// grid (32, 24): which = blockIdx.y>>3 (0=q fp32, 1=k bf16, 2=v -> vt hi/lo).
// Staging is now a pure bf16 copy (2 uint4 loads + 2 LDS stores per vthread);
// the fp32->bf16 conversion was hoisted to convert_bf16 (was 16 f2b + 4
// float4 loads per vthread per k0 -- the GEMM's VALU bottleneck).
// ---------------------------------------------------------------------------
__global__ __launch_bounds__(256) void gemm_qkv(
    const u16* __restrict__ xb,
    const u16* __restrict__ wqb, const u16* __restrict__ wkb, const u16* __restrict__ wvb,
    const float* __restrict__ bq, const float* __restrict__ bk, const float* __restrict__ bv,
    float* __restrict__ qout, u16* __restrict__ kout,
    u16* __restrict__ vthi, u16* __restrict__ vtlo)
{
    __shared__ u16 xs[64 * 72];
    __shared__ u16 wsl[64 * 72];
    int tid = threadIdx.x;
    int lane = tid & 63;
    int wv = tid >> 6;
    int lo = lane & 15, hi = lane >> 4;
    int which = blockIdx.y >> 3;
    int m0 = blockIdx.x * 64, n0 = (blockIdx.y & 7) * 64;
    const u16*   W    = which == 0 ? wqb : (which == 1 ? wkb : wvb);
    const float* bias = which == 0 ? bq  : (which == 1 ? bk  : bv);

    floatx4 acc[4];
#pragma unroll
    for (int mt = 0; mt < 4; ++mt) acc[mt] = (floatx4){0.f, 0.f, 0.f, 0.f};

    for (int k0 = 0; k0 < 512; k0 += 64) {
        __syncthreads();
#pragma unroll
        for (int i = 0; i < 2; ++i) {
            int v = tid + i * 256;
            int row = v >> 3, c8 = (v & 7) * 8;
            *(uint4*)(xs + row * 72 + c8)  = *(const uint4*)(xb + (m0 + row) * 512 + k0 + c8);
            *(uint4*)(wsl + row * 72 + c8) = *(const uint4*)(W  + (n0 + row) * 512 + k0 + c8);
        }
        __syncthreads();
#pragma unroll
        for (int ks = 0; ks < 2; ++ks) {
            short8 bfr = *(const short8*)(wsl + (wv * 16 + lo) * 72 + ks * 32 + hi * 8);
#pragma unroll
            for (int mt = 0; mt < 4; ++mt) {
                short8 afr = *(const short8*)(xs + (mt * 16 + lo) * 72 + ks * 32 + hi * 8);
                acc[mt] = __builtin_amdgcn_mfma_f32_16x16x32_bf16(afr, bfr, acc[mt], 0, 0, 0);
            }
        }
    }

    int n = n0 + wv * 16 + lo;
    float bv2 = bias[n];
    if (which == 2) {
        // transpose V tile through LDS; emit vt_hi/vt_lo bf16 [bh][d][c]
        __syncthreads();                           // xs/wsl reuse: all waves done with MFMAs
        int nl = wv * 16 + lo;                     // local d
#pragma unroll
        for (int mt = 0; mt < 4; ++mt)
#pragma unroll
            for (int r = 0; r < 4; ++r) {
                int ml = mt * 16 + hi * 4 + r;     // local c
                float y = acc[mt][r] + bv2;
                u16 vh = f2b(y);
                u16 vl = f2b(y - b2f(vh));
                xs[nl * 72 + ml]  = vh;
                wsl[nl * 72 + ml] = vl;
            }
        __syncthreads();
        int row = tid >> 2, seg = (tid & 3) * 16;  // row = local d, seg = local c chunk
        int b = m0 >> 10, c0 = m0 & 1023, h2 = n0 >> 6;
        size_t dst = ((size_t)((b * 8 + h2) * 64 + row)) * 1024 + c0 + seg;
        *(uint4*)(vthi + dst)     = *(uint4*)(xs  + row * 72 + seg);
        *(uint4*)(vthi + dst + 8) = *(uint4*)(xs  + row * 72 + seg + 8);
        *(uint4*)(vtlo + dst)     = *(uint4*)(wsl + row * 72 + seg);
        *(uint4*)(vtlo + dst + 8) = *(uint4*)(wsl + row * 72 + seg + 8);
    } else {
        int h = n >> 6, dd = n & 63;
#pragma unroll
        for (int mt = 0; mt < 4; ++mt)
#pragma unroll
            for (int r = 0; r < 4; ++r) {
                int m = m0 + mt * 16 + hi * 4 + r;  // C/D: row=(lane>>4)*4+reg, col=lane&15
                float y = acc[mt][r] + bv2;
                int b = m >> 10, c = m & 1023;
                int idx = (((b * 8 + h) * 1024) + c) * 64 + dd;
                if (which == 0) qout[idx] = y;
                else            kout[idx] = f2b(y);
            }
    }
}

// ---------------------------------------------------------------------------
// Output GEMM: Y[m,n] = sum_k A[m,k]*Wo[n,k] + bo[n], fp32 out, [m*512+n].
// (fp32 path kept: Wo can't be pre-converted safely -- it is consumed after
// attn overwrites the overlay region.)
// ---------------------------------------------------------------------------
__global__ __launch_bounds__(256) void gemm_out(
    const float* __restrict__ A, const float* __restrict__ W, const float* __restrict__ bias,
    float* __restrict__ outf)
{
    __shared__ u16 xs[64 * 72];
    __shared__ u16 wsl[64 * 72];
    int tid = threadIdx.x;
    int lane = tid & 63;
    int wv = tid >> 6;
    int lo = lane & 15, hi = lane >> 4;
    int m0 = blockIdx.x * 64, n0 = blockIdx.y * 64;

    floatx4 acc[4];
#pragma unroll
    for (int mt = 0; mt < 4; ++mt) acc[mt] = (floatx4){0.f, 0.f, 0.f, 0.f};

    for (int k0 = 0; k0 < 512; k0 += 64) {
        __syncthreads();
#pragma unroll
        for (int i = 0; i < 2; ++i) {
            int v = tid + i * 256;
            int row = v >> 3, c8 = (v & 7) * 8;
            const float* ap = A + (m0 + row) * 512 + k0 + c8;
            const float* wp = W + (n0 + row) * 512 + k0 + c8;
            float4 a0 = *(const float4*)(ap);
            float4 a1 = *(const float4*)(ap + 4);
            float4 w0 = *(const float4*)(wp);
            float4 w1v = *(const float4*)(wp + 4);
            union { u16 u[8]; uint4 q; } ca, cw;
            ca.u[0] = f2b(a0.x); ca.u[1] = f2b(a0.y); ca.u[2] = f2b(a0.z); ca.u[3] = f2b(a0.w);
            ca.u[4] = f2b(a1.x); ca.u[5] = f2b(a1.y); ca.u[6] = f2b(a1.z); ca.u[7] = f2b(a1.w);
            cw.u[0] = f2b(w0.x); cw.u[1] = f2b(w0.y); cw.u[2] = f2b(w0.z); cw.u[3] = f2b(w0.w);
            cw.u[4] = f2b(w1v.x); cw.u[5] = f2b(w1v.y); cw.u[6] = f2b(w1v.z); cw.u[7] = f2b(w1v.w);
            *(uint4*)(xs + row * 72 + c8)  = ca.q;
            *(uint4*)(wsl + row * 72 + c8) = cw.q;
        }
        __syncthreads();
#pragma unroll
        for (int ks = 0; ks < 2; ++ks) {
            short8 bfr = *(const short8*)(wsl + (wv * 16 + lo) * 72 + ks * 32 + hi * 8);
#pragma unroll
            for (int mt = 0; mt < 4; ++mt) {
                short8 afr = *(const short8*)(xs + (mt * 16 + lo) * 72 + ks * 32 + hi * 8);
                acc[mt] = __builtin_amdgcn_mfma_f32_16x16x32_bf16(afr, bfr, acc[mt], 0, 0, 0);
            }
        }
    }

    int n = n0 + wv * 16 + lo;
    float bv = bias[n];
#pragma unroll
    for (int mt = 0; mt < 4; ++mt)
#pragma unroll
        for (int r = 0; r < 4; ++r) {
            int m = m0 + mt * 16 + hi * 4 + r;
            outf[m * 512 + n] = acc[mt][r] + bv;
        }
}

// ---------------------------------------------------------------------------
// Fused second-order attention, EXACT v24 (best verified: attn 403 us,
// total 449): LDS-staged K via global_load_lds + both-sides XOR swizzle.
// v25's deferred-tail restructure regressed (+17 MB scratch) and is reverted.
// ---------------------------------------------------------------------------
#define CHUNK_LOAD(BUFI)                                                       \
    {                                                                          \
        bf[0][0] = *(const short8*)(kr0 + (BUFI) * 2048);                      \
        bf[0][1] = *(const short8*)(kr1 + (BUFI) * 2048);                      \
        bf[1][0] = *(const short8*)(kr0 + (BUFI) * 2048 + 1024);               \
        bf[1][1] = *(const short8*)(kr1 + (BUFI) * 2048 + 1024);               \
        kstage(kg, kstg + (((BUFI) ^ 1) * 2048));                              \
        kg += 2048;                                                            \
    }

#define CHUNK_SCORE(CIDX)                                                      \
    {                                                                          \
        floatx2 s0v = (floatx2){0.f, 0.f};                                     \
        floatx2 s1v = (floatx2){0.f, 0.f};                                     \
        floatx4 aP[2], aN[2];                                                  \
        aP[0] = __builtin_amdgcn_mfma_f32_16x16x32_bf16(af[0][0], bf[0][0], qpinit[0], 0, 0, 0); \
        aP[0] = __builtin_amdgcn_mfma_f32_16x16x32_bf16(af[0][1], bf[0][1], aP[0], 0, 0, 0); \
        aP[1] = __builtin_amdgcn_mfma_f32_16x16x32_bf16(af[0][0], bf[1][0], qpinit[0], 0, 0, 0); \
        aP[1] = __builtin_amdgcn_mfma_f32_16x16x32_bf16(af[0][1], bf[1][1], aP[1], 0, 0, 0); \
        _Pragma("unroll")                                                      \
        for (int mt = 0; mt < 4; ++mt) {                                       \
            if (mt < 3) {                                                      \
                aN[0] = __builtin_amdgcn_mfma_f32_16x16x32_bf16(af[mt + 1][0], bf[0][0], qpinit[mt + 1], 0, 0, 0); \
                aN[0] = __builtin_amdgcn_mfma_f32_16x16x32_bf16(af[mt + 1][1], bf[0][1], aN[0], 0, 0, 0); \
                aN[1] = __builtin_amdgcn_mfma_f32_16x16x32_bf16(af[mt + 1][0], bf[1][0], qpinit[mt + 1], 0, 0, 0); \
                aN[1] = __builtin_amdgcn_mfma_f32_16x16x32_bf16(af[mt + 1][1], bf[1][1], aN[1], 0, 0, 0); \
            }                                                                  \
            _Pragma("unroll")                                                  \
            for (int h2 = 0; h2 < 2; ++h2) {                                   \
                u32 wp = wcp[mt][h2];                                          \
                floatx2 wv2 = (floatx2){u2f(wp << 16), u2f(wp & 0xFFFF0000u)}; \
                _Pragma("unroll")                                              \
                for (int t = 0; t < 2; ++t) {                                  \
                    floatx2 x = (floatx2){aP[t][h2 * 2 + 0], aP[t][h2 * 2 + 1]}; \
                    floatx2 ex = (floatx2){__builtin_amdgcn_exp2f(x.x),        \
                                           __builtin_amdgcn_exp2f(x.y)};       \
                    floatx2 a = ex + 1.0f;                                     \
                    float rc = __builtin_amdgcn_rcpf(a.x * a.y);               \
                    floatx2 sw = (floatx2){a.y, a.x};                          \
                    floatx2 contrib = (x * wv2) * (sw * rc);                   \
                    if (t == 0) s0v += contrib; else s1v += contrib;           \
                }                                                              \
            }                                                                  \
            aP[0] = aN[0];                                                     \
            aP[1] = aN[1];                                                     \
        }                                                                      \
        float s0 = s0v.x + s0v.y, s1 = s1v.x + s1v.y;                          \
        s0 += __shfl_xor(s0, 16); s0 += __shfl_xor(s0, 32);                    \
        s1 += __shfl_xor(s1, 16); s1 += __shfl_xor(s1, 32);                    \
        float p0 = __builtin_amdgcn_exp2f(s0 - 16.0f);                         \
        float p1 = __builtin_amdgcn_exp2f(s1 - 16.0f);                         \
        u16 ph0 = f2b(p0);                                                     \
        u16 ph1 = f2b(p1);                                                     \
        l_run += b2f(ph0) + b2f(ph1);                                          \
        u16* pw = gw + (CIDX) * 528;                                           \
        if (lane < 16) {                                                       \
            pw[((lo >> 3) * 16 + wv) * 8 + (lo & 7)] = ph0;                    \
            pw[((2 + (lo >> 3)) * 16 + wv) * 8 + (lo & 7)] = ph1;              \
        }                                                                      \
    }

#define PV_GROUP(PGW)                                                          \
    {                                                                          \
        const u16* vlp = vhp + (1u << 20);         /* vtlo = vthi + 2MB */     \
        _Pragma("unroll")                                                      \
        for (int c2 = 0; c2 < 4; ++c2) {                                       \
            uint4 vh = *(const uint4*)(vhp + c2 * 32);                         \
            uint4 vl = *(const uint4*)(vlp + c2 * 32);                         \
            short8 pf = *(const short8*)((PGW) + c2 * 528 + lane * 8);         \
            pvacc = __builtin_amdgcn_mfma_f32_16x16x32_bf16(pf, *(short8*)&vh, pvacc, 0, 0, 0); \
            pvacc = __builtin_amdgcn_mfma_f32_16x16x32_bf16(pf, *(short8*)&vl, pvacc, 0, 0, 0); \
        }                                                                      \
        vhp += 128;                                                            \
    }

__global__ __launch_bounds__(256, 4) void attn26(
    const float* __restrict__ qf, const u16* __restrict__ kb,
    const u16* __restrict__ vthi, const u16* __restrict__ vtlo,
    const float* __restrict__ w1, const float* __restrict__ b1, const float* __restrict__ w2,
    float* __restrict__ ao)
{
    __shared__ float q_l[4 * 64];
    __shared__ __align__(16) u16 plds[2 * 4 * 528];   // [dbuf][chunk plane 528][A-frag order]
    __shared__ __align__(16) u16 kbuf[2 * 2048];      // 2 x 4KB K-chunk ring (col-swizzled)
    __shared__ float l_sh[4];
    int tid = threadIdx.x;
    int lane = tid & 63;
    int wv = tid >> 6;
    int lo = lane & 15, hi = lane >> 4;
    int bh = blockIdx.x >> 8;                      // 0..15 = b*8+h
    int qbase = (blockIdx.x & 255) << 2;           // block's first query
    int qi = qbase | wv;                           // this wave's query

    const float NA = -2.45546696f;                 // -1.702 * log2(e)

    // zero p-LDS once: A-frag rows q=4..15 must stay 0 so PV C rows 4..15 are clean
    for (int i = tid; i < 2112; i += 256) ((u32*)plds)[i] = 0;

    q_l[wv * 64 + lane] = qf[(bh * 1024 + qi) * 64 + lane];

    // qp[e]+b1[e] at lane=e
    float qpacc = b1[lane];
#pragma unroll
    for (int d8 = 0; d8 < 64; d8 += 8) {
        float4 wa = *(const float4*)(w1 + lane * 192 + d8);
        float4 wb = *(const float4*)(w1 + lane * 192 + d8 + 4);
        const float* q8 = q_l + wv * 64 + d8;      // wave-uniform broadcast reads
        qpacc = __builtin_fmaf(q8[0], wa.x, qpacc);
        qpacc = __builtin_fmaf(q8[1], wa.y, qpacc);
        qpacc = __builtin_fmaf(q8[2], wa.z, qpacc);
        qpacc = __builtin_fmaf(q8[3], wa.w, qpacc);
        qpacc = __builtin_fmaf(q8[4], wb.x, qpacc);
        qpacc = __builtin_fmaf(q8[5], wb.y, qpacc);
        qpacc = __builtin_fmaf(q8[6], wb.z, qpacc);
        qpacc = __builtin_fmaf(q8[7], wb.w, qpacc);
    }
    qpacc *= NA;                                   // qp' = c * (qp + b1)

    // w2c packed: wc' = w2[e] * (1/8)*log2e / c = w2[e] * -0.07344288
    u32 wcp[4][2];
    float w2row = w2[lane] * -0.07344288f;
#pragma unroll
    for (int mt = 0; mt < 4; ++mt)
#pragma unroll
        for (int h2 = 0; h2 < 2; ++h2) {
            int e0 = mt * 16 + hi * 4 + h2 * 2;
            u32 lo16 = (u32)f2b(__shfl(w2row, e0));
            u32 hi16 = (u32)f2b(__shfl(w2row, e0 + 1));
            wcp[mt][h2] = (hi16 << 16) | lo16;
        }

    // q pieces for frag build: qv2[ks][j] = q[ks*32 + hi*8 + j]
    float qv2[2][8];
#pragma unroll
    for (int ks = 0; ks < 2; ++ks)
#pragma unroll
        for (int j = 0; j < 8; ++j)
            qv2[ks][j] = q_l[wv * 64 + ks * 32 + hi * 8 + j];

    // A-frags: c * qw'[e = mt*16+lo][dd = ks*32 + hi*8 + j], bf16
    short8 af[4][2];
#pragma unroll
    for (int mt = 0; mt < 4; ++mt) {
        const float* wr = w1 + (mt * 16 + lo) * 192;
#pragma unroll
        for (int ks = 0; ks < 2; ++ks) {
            int dd0 = ks * 32 + hi * 8;
            float4 a0 = *(const float4*)(wr + 128 + dd0);
            float4 a1 = *(const float4*)(wr + 128 + dd0 + 4);
            float4 k0 = *(const float4*)(wr + 64 + dd0);
            float4 k1 = *(const float4*)(wr + 64 + dd0 + 4);
            union { u16 u[8]; short8 s; } cv;
            cv.u[0] = f2b(NA * __builtin_fmaf(qv2[ks][0], a0.x, k0.x));
            cv.u[1] = f2b(NA * __builtin_fmaf(qv2[ks][1], a0.y, k0.y));
            cv.u[2] = f2b(NA * __builtin_fmaf(qv2[ks][2], a0.z, k0.z));
            cv.u[3] = f2b(NA * __builtin_fmaf(qv2[ks][3], a0.w, k0.w));
            cv.u[4] = f2b(NA * __builtin_fmaf(qv2[ks][4], a1.x, k1.x));
            cv.u[5] = f2b(NA * __builtin_fmaf(qv2[ks][5], a1.y, k1.y));
            cv.u[6] = f2b(NA * __builtin_fmaf(qv2[ks][6], a1.z, k1.z));
            cv.u[7] = f2b(NA * __builtin_fmaf(qv2[ks][7], a1.w, k1.w));
            af[mt][ks] = cv.s;
        }
    }

    // rank-1 qp' C-init, loop-invariant (v18-verified)
    floatx4 qpinit[4];
    {
        const floatx4 z = (floatx4){0.f, 0.f, 0.f, 0.f};
        union { u16 u[8]; short8 s; } bb;
#pragma unroll
        for (int i = 0; i < 8; ++i) bb.u[i] = 0;
        bb.u[0] = (hi == 0) ? (u16)0x3F80 : (u16)0;   // bf16 1.0 at k=0
#pragma unroll
        for (int mt = 0; mt < 4; ++mt) {
            float qpv = __shfl(qpacc, mt * 16 + lo);
            union { u16 u[8]; short8 s; } aa;
#pragma unroll
            for (int i = 0; i < 8; ++i) aa.u[i] = 0;
            aa.u[0] = (hi == 0) ? f2b(qpv) : (u16)0;
            qpinit[mt] = __builtin_amdgcn_mfma_f32_16x16x32_bf16(aa.s, bb.s, z, 0, 0, 0);
        }
    }

    // K staging source with col-swizzle pre-applied on the GLOBAL address:
    // lane's LDS slot s = wv*64+lane holds (row = s>>3, col = s&7); it must
    // load global 16B unit (row, col ^ (row&7)). row&7 = lane>>3 here.
    const u16* kg = kb + bh * 65536
                  + (wv * 8 + (lane >> 3)) * 64
                  + (((lane & 7) ^ (lane >> 3)) * 8);
    u16* kstg = kbuf + wv * 512;                   // linear LDS dest (wave-uniform + lane*16B)
    kstage(kg, kstg);                              // stage chunk 0 into kbuf[0]
    kg += 2048;

    // swizzled per-lane read bases: row lo, cols ksw / ksw^4 (rows +16 share lo&7)
    int ksw = hi ^ (lo & 7);
    const u16* kr0 = kbuf + lo * 64 + ksw * 8;
    const u16* kr1 = kbuf + lo * 64 + (ksw ^ 4) * 8;

    // drains chunk-0 staging (vmcnt) + plds zero-init + q_l, block-wide
    __syncthreads();

    float l_run = 0.f;
    floatx4 pvacc = (floatx4){0.f, 0.f, 0.f, 0.f};   // out[q=row 0..3][d = wv*16+col]
    // V^T B-frag base: this wave's d-tile row = wv*16+lo, k-offset hi*8
    const u16* vhp = vthi + bh * 65536 + (wv * 16 + lo) * 1024 + hi * 8;
    short8 bf[2][2];

    for (int g = 0; g < 8; ++g) {
        u16* gw  = plds + (g & 1) * (4 * 528);         // this group's write buffer
        u16* pgw = plds + ((g & 1) ^ 1) * (4 * 528);   // previous group's buffer

        // chunk 4g+0 (kbuf parity 0)
        CHUNK_LOAD(0)
        if (g > 0) { PV_GROUP(pgw) }                   // PV for group g-1
        CHUNK_SCORE(0)
        __syncthreads();
        // chunk 4g+1
        CHUNK_LOAD(1)
        CHUNK_SCORE(1)
        __syncthreads();
        // chunk 4g+2
        CHUNK_LOAD(0)
        CHUNK_SCORE(2)
        __syncthreads();
        // chunk 4g+3
        CHUNK_LOAD(1)
        CHUNK_SCORE(3)
        __syncthreads();
    }

    // trailing PV for group 7 (plds[1]); publishes drained by the loop's last barrier
    PV_GROUP(plds + (4 * 528))

    float l = l_run;
    l += __shfl_xor(l, 1); l += __shfl_xor(l, 2);
    l += __shfl_xor(l, 4); l += __shfl_xor(l, 8);
    if (lane == 0) l_sh[wv] = l;
    __syncthreads();

    if (hi == 0) {                                 // C rows 0..3 live on lanes 0..15
        int b = bh >> 3, h = bh & 7;
#pragma unroll
        for (int q = 0; q < 4; ++q) {
            float outv = pvacc[q] * __builtin_amdgcn_rcpf(l_sh[q]);
            ao[((b * 1024 + qbase + q) * 512) + h * 64 + wv * 16 + lo] = outv;
        }
    }
}
#undef CHUNK_LOAD
#undef CHUNK_SCORE
#undef PV_GROUP

// ---------------------------------------------------------------------------
extern "C" void kernel_launch(void* const* d_in, const int* in_sizes, int n_in,
                              void* d_out, int out_size, void* d_ws, size_t ws_size,
                              hipStream_t stream)
{
    (void)in_sizes; (void)n_in; (void)out_size; (void)ws_size;
    const float* x  = (const float*)d_in[0];
    const float* Wq = (const float*)d_in[1];
    const float* bq = (const float*)d_in[2];
    const float* Wk = (const float*)d_in[3];
    const float* bk = (const float*)d_in[4];
    const float* Wv = (const float*)d_in[5];
    const float* bv = (const float*)d_in[6];
    const float* w1 = (const float*)d_in[7];
    const float* b1 = (const float*)d_in[8];
    const float* w2 = (const float*)d_in[9];
    // d_in[10] = b2: scalar shift of all scores -> softmax-invariant -> unused
    const float* Wo = (const float*)d_in[11];
    const float* bo = (const float*)d_in[12];

    char* ws = (char*)d_ws;
    float* q_ws = (float*)(ws);               // 4 MB fp32 (b,h,c,d)
    u16*   k_ws = (u16*)(ws + (4u << 20));    // 2 MB bf16 (b,h,c,d)
    u16*   vthi = (u16*)(ws + (6u << 20));    // 2 MB bf16 V^T hi (b,h,d,c)
    u16*   vtlo = (u16*)(ws + (8u << 20));    // 2 MB bf16 V^T lo (b,h,d,c) (MUST stay vthi+2MB)
    float* a_ws = (float*)(ws + (10u << 20)); // 4 MB fp32 (b,c,D)
    // bf16 pre-convert OVERLAY in the a_ws region [10,13.5) MB:
    //   lifetime: written by convert_bf16, read by gemm_qkv, then dead
    //   before attn writes a_ws (launches are serial on one stream).
    u16* cvt = (u16*)(ws + (10u << 20));      // xb[1048576] | wqb | wkb | wvb
    u16* xb  = cvt;
    u16* wqb = cvt + 1048576;
    u16* wkb = cvt + 1310720;
    u16* wvb = cvt + 1572864;

    dim3 blk(256);
    hipLaunchKernelGGL(convert_bf16, dim3(896), blk, 0, stream, x, Wq, Wk, Wv, cvt);
    hipLaunchKernelGGL(gemm_qkv, dim3(32, 24), blk, 0, stream,
                       xb, wqb, wkb, wvb, bq, bk, bv, q_ws, k_ws, vthi, vtlo);
    hipLaunchKernelGGL(attn26, dim3(4096), blk, 0, stream,
                       q_ws, k_ws, vthi, vtlo, w1, b1, w2, a_ws);
    hipLaunchKernelGGL(gemm_out, dim3(32, 8), blk, 0, stream, a_ws, Wo, bo, (float*)d_out);
}